// Round 5
// baseline (443.657 us; speedup 1.0000x reference)
//
#include <hip/hip_runtime.h>
#include <stdint.h>

// Round-9: drop the Gram entirely — every output is O(D*P):
//   rowsums rsT/rsR (LDS atomics), column sumsq q/e (register acc, fixed c),
//   a[p]=sum_d T[d][p]*rsR[d], b[p] (pass B1, L2/L3-hot re-read),
//   m2/r2/mr from rowsums, u2/v2/uv = per-row dots with topk weights (pass B2,
//   re-read + LDS-atomic row reduce). All passes coalesced (c = t%9 fixed
//   since NT=576 ≡ 0 mod 9). ~150K FMA/group (9x less than round-4 Gram),
//   ~no LDS-pipe pressure. Should land on the HBM stream roofline.
#define NGRP 1500
#define DD   512
#define PP   36
#define DP   (DD*PP)          // 18432 floats per tensor per group
#define NT   576              // 9 waves; 4608 float4 per tensor = NT*8
#define NK   8
#define SCALE_CLS 7.0f
#define EPS 1e-12f

__device__ __forceinline__ float waveRed(float x){
  #pragma unroll
  for (int off = 32; off; off >>= 1) x += __shfl_xor(x, off, 64);
  return x;
}

__global__ __launch_bounds__(NT, 5)   // 5 waves/EU -> 20 waves/CU -> 2 blocks
void topk_fuse(const float* __restrict__ gtrain,
               const float* __restrict__ gtest,
               const int* __restrict__ Kp,
               float* __restrict__ out)
{
  __shared__ float s_rsT[DD], s_rsR[DD];         // row sums (2 KB each pair)
  __shared__ float s_u[DD], s_v[DD];             // fuse row dots
  __shared__ float s_q[PP], s_e[PP];             // column sumsq
  __shared__ float s_a[PP], s_b[PP];             // column dots with rowsums
  __shared__ float s_nt[PP], s_nr[PP];           // per-pos norms
  __shared__ float s_st[PP], s_sr[PP];           // ranking scores
  __shared__ __align__(16) float s_wt[PP];       // fuse weights (test)
  __shared__ __align__(16) float s_wr[PP];       // fuse weights (train)
  __shared__ float s_red[24];

  const int t    = threadIdx.x;
  const int lane = t & 63;
  const int wave = t >> 6;                       // 0..8
  const int g    = blockIdx.x;
  const int K    = Kp[0];
  const int c    = t % 9;                        // fixed column-block
  const int d0   = t / 9;                        // row within chunk 0

  const float4* gT4 = (const float4*)(gtest  + (size_t)g * DP);
  const float4* gR4 = (const float4*)(gtrain + (size_t)g * DP);

  if (t < DD) { s_rsT[t] = 0.f; s_rsR[t] = 0.f; s_u[t] = 0.f; s_v[t] = 0.f; }
  if (t < PP) { s_q[t] = 0.f; s_e[t] = 0.f; s_a[t] = 0.f; s_b[t] = 0.f; }
  __syncthreads();                                              // 1

  // ---- Pass A (HBM stream): rowsums + column sumsq. ----
  float qx=0,qy=0,qz=0,qw=0, ex=0,ey=0,ez=0,ew=0;
  #pragma unroll
  for (int k = 0; k < NK; ++k) {
    const int i = t + NT*k;
    float4 x = gT4[i];
    float4 y = gR4[i];
    atomicAdd(&s_rsT[d0 + 64*k], (x.x + x.y) + (x.z + x.w));
    atomicAdd(&s_rsR[d0 + 64*k], (y.x + y.y) + (y.z + y.w));
    qx += x.x*x.x; qy += x.y*x.y; qz += x.z*x.z; qw += x.w*x.w;
    ex += y.x*y.x; ey += y.y*y.y; ez += y.z*y.z; ew += y.w*y.w;
  }
  {
    const int p0 = 4*c;
    atomicAdd(&s_q[p0+0], qx); atomicAdd(&s_q[p0+1], qy);
    atomicAdd(&s_q[p0+2], qz); atomicAdd(&s_q[p0+3], qw);
    atomicAdd(&s_e[p0+0], ex); atomicAdd(&s_e[p0+1], ey);
    atomicAdd(&s_e[p0+2], ez); atomicAdd(&s_e[p0+3], ew);
  }
  __syncthreads();                                              // 2

  // ---- Mean-cosine partials from rowsums (1/36 factors cancel). ----
  if (t < DD) {
    float rT = s_rsT[t], rR = s_rsR[t];
    float m2 = waveRed(rT * rT);
    float r2 = waveRed(rR * rR);
    float mr = waveRed(rT * rR);
    if (lane == 0) { s_red[wave] = m2; s_red[8+wave] = r2; s_red[16+wave] = mr; }
  }

  // ---- Pass B1 (L2/L3-hot re-read): a[p], b[p]. ----
  float ax=0,ay=0,az=0,aw=0, bx=0,by=0,bz=0,bw=0;
  #pragma unroll
  for (int k = 0; k < NK; ++k) {
    const int i = t + NT*k;
    float4 x = gT4[i];
    float4 y = gR4[i];
    const float rr = s_rsR[d0 + 64*k];
    const float rt = s_rsT[d0 + 64*k];
    ax += x.x*rr; ay += x.y*rr; az += x.z*rr; aw += x.w*rr;
    bx += y.x*rt; by += y.y*rt; bz += y.z*rt; bw += y.w*rt;
  }
  {
    const int p0 = 4*c;
    atomicAdd(&s_a[p0+0], ax); atomicAdd(&s_a[p0+1], ay);
    atomicAdd(&s_a[p0+2], az); atomicAdd(&s_a[p0+3], aw);
    atomicAdd(&s_b[p0+0], bx); atomicAdd(&s_b[p0+1], by);
    atomicAdd(&s_b[p0+2], bz); atomicAdd(&s_b[p0+3], bw);
  }
  __syncthreads();                                              // 3

  // ---- Global (mean-cosine) score. ----
  if (t == 0) {
    float m2 = 0.f, r2 = 0.f, mr = 0.f;
    #pragma unroll
    for (int w = 0; w < 8; ++w) { m2 += s_red[w]; r2 += s_red[8+w]; mr += s_red[16+w]; }
    out[g] = SCALE_CLS * mr / (fmaxf(sqrtf(m2), EPS) * fmaxf(sqrtf(r2), EPS));
  }

  // ---- Norms + ranking scores (positive common factors dropped). ----
  if (wave < 2 && lane < PP) {
    float q  = wave ? s_e[lane] : s_q[lane];
    float dm = wave ? s_b[lane] : s_a[lane];
    float n  = fmaxf(sqrtf(q), EPS);
    float sc = dm / n;
    if (wave) { s_nr[lane] = n; s_sr[lane] = sc; }
    else      { s_nt[lane] = n; s_st[lane] = sc; }
  }
  __syncthreads();                                              // 4

  // ---- Top-K via ranks (jnp ties: lower index wins) -> fuse weights. ----
  if (wave < 2 && lane < PP) {
    const float* sc = wave ? s_sr : s_st;
    const float* nn = wave ? s_nr : s_nt;
    float*       w  = wave ? s_wr : s_wt;
    float mine = sc[lane];
    int rank = 0;
    #pragma unroll
    for (int p = 0; p < PP; ++p) {
      float o = sc[p];
      rank += ((o > mine) || (o == mine && p < lane)) ? 1 : 0;
    }
    w[lane] = (rank < K) ? (1.0f / nn[lane]) : 0.f;
  }
  __syncthreads();                                              // 5

  // ---- Pass B2 (hot re-read): per-row fuse dots u_d, v_d. ----
  {
    const float4 wt = *(const float4*)&s_wt[4*c];
    const float4 wr = *(const float4*)&s_wr[4*c];
    #pragma unroll
    for (int k = 0; k < NK; ++k) {
      const int i = t + NT*k;
      float4 x = gT4[i];
      float4 y = gR4[i];
      float up = x.x*wt.x + x.y*wt.y + x.z*wt.z + x.w*wt.w;
      float vp = y.x*wr.x + y.y*wr.y + y.z*wr.z + y.w*wr.w;
      atomicAdd(&s_u[d0 + 64*k], up);
      atomicAdd(&s_v[d0 + 64*k], vp);
    }
  }
  __syncthreads();                                              // 6

  // ---- Fuse cosine: u2, v2, uv over rows. ----
  if (t < DD) {
    float u = s_u[t], v = s_v[t];
    float u2 = waveRed(u * u);
    float v2 = waveRed(v * v);
    float uv = waveRed(u * v);
    if (lane == 0) { s_red[wave] = u2; s_red[8+wave] = v2; s_red[16+wave] = uv; }
  }
  __syncthreads();                                              // 7

  if (t == 0) {
    float u2 = 0.f, v2 = 0.f, uv = 0.f;
    #pragma unroll
    for (int w = 0; w < 8; ++w) { u2 += s_red[w]; v2 += s_red[8+w]; uv += s_red[16+w]; }
    out[NGRP + g] = SCALE_CLS * uv / (fmaxf(sqrtf(u2), EPS) * fmaxf(sqrtf(v2), EPS));
  }
}

extern "C" void kernel_launch(void* const* d_in, const int* in_sizes, int n_in,
                              void* d_out, int out_size, void* d_ws, size_t ws_size,
                              hipStream_t stream)
{
  const float* ftrain = (const float*)d_in[0];
  const float* ftest  = (const float*)d_in[1];
  const int*   Kp     = (const int*)d_in[2];
  float*       out    = (float*)d_out;
  topk_fuse<<<NGRP, NT, 0, stream>>>(ftrain, ftest, Kp, out);
}